// Round 4
// baseline (135.228 us; speedup 1.0000x reference)
//
#include <hip/hip_runtime.h>
#include <hip/hip_bf16.h>

#define BB   4
#define CC   128
#define HH   192
#define WWd  192
#define HWp  (HH*WWd)      // 36864
#define OO   128
#define KK   7
#define NPIX (BB*HWp)      // 147456
#define TILE 64
#define XT_PITCH 136       // shorts: 272 B rows, 16B-aligned (b128-read validated in round 1)

typedef short bf16x8 __attribute__((ext_vector_type(8)));
typedef float f32x4  __attribute__((ext_vector_type(4)));

static __device__ __forceinline__ unsigned short f2bf(float f) {
    union { __hip_bfloat16 h; unsigned short u; } cvt;
    cvt.h = __float2bfloat16(f);
    return cvt.u;
}

// ---- prep: Wsum[o][c] = sum_k kernel_w[o*7+k, c] -> bf16 in MFMA A-frag order;
//      bsum[o] = sum_k kernel_b[o*7+k] (fp32).  (validated rounds 1 & 3)
__global__ __launch_bounds__(256) void prep_kernel(const float* __restrict__ kw,
                                                   const float* __restrict__ kb,
                                                   unsigned short* __restrict__ wfrag,
                                                   float* __restrict__ bsum) {
    int tid = blockIdx.x * 256 + threadIdx.x;   // 0..16383
    int o = tid >> 7, c = tid & 127;
    float s = 0.f;
#pragma unroll
    for (int k = 0; k < KK; ++k) s += kw[(o*KK + k)*CC + c];
    // conv reads: afrag[ks] of wave w, lane l, elem j <-> o = w*16+(l&15), c = ks*32+(l>>4)*8+j
    int mt8 = o >> 4, lo = o & 15;
    int ks = c >> 5, g = (c >> 3) & 3, j = c & 7;
    int idx = (((mt8*4 + ks)*64) + (lo + 16*g))*8 + j;
    wfrag[idx] = f2bf(s);
    if (c == 0) {
        float bs = 0.f;
#pragma unroll
        for (int k = 0; k < KK; ++k) bs += kb[o*KK + k];
        bsum[o] = bs;
    }
}

// ---- main: 512 threads = 8 waves; block = 64 pixels x 128 outputs; wave = 16 outputs.
// Single LDS pass: lane<->pixel coalesced scalar loads give each thread 4 consecutive
// channels of one pixel -> bf16x4 -> one ds_write_b64 into xT[pix][c]. One barrier.
__global__ __launch_bounds__(512, 6) void conv_kernel(const float* __restrict__ x,
                                                      const unsigned short* __restrict__ wfrag,
                                                      const float* __restrict__ bsum,
                                                      float* __restrict__ out) {
    __shared__ __align__(16) unsigned short xT[TILE][XT_PITCH];  // 17408 B
    __shared__ float sPart[TILE][9];                             // 2304 B (pad 9 -> conflict-free)

    const int t = threadIdx.x;
    const int w = t >> 6;            // wave 0..7: output group o in [w*16, w*16+16)
    const int l = t & 63;
    const int lo16 = l & 15, g4 = l >> 4;

    const int pixBase = blockIdx.x * TILE;
    const int bIdx   = pixBase / HWp;
    const int hw     = pixBase - bIdx * HWp;     // multiple of 64
    const float* xb  = x + (size_t)bIdx * CC * HWp + hw;

    // A-fragments (Wsum) hoisted: 4 k-steps, 16 VGPR; wfrag is L2-resident
    bf16x8 afrag[4];
#pragma unroll
    for (int ks = 0; ks < 4; ++ks)
        afrag[ks] = *reinterpret_cast<const bf16x8*>(wfrag + ((size_t)(w*4 + ks)*64 + l)*8);

    // Stage A: thread -> pixel l, channel quads q = w + 8*it; 4 coalesced dword loads each
    float csum = 0.f;
#pragma unroll
    for (int it = 0; it < 4; ++it) {
        const int q = w + 8*it;                 // channel quad 0..31
        const float* src = xb + (size_t)(4*q) * HWp + l;
        float v0 = src[0];
        float v1 = src[(size_t)HWp];
        float v2 = src[(size_t)2*HWp];
        float v3 = src[(size_t)3*HWp];
        csum += v0 + v1 + v2 + v3;
        uint2 u;
        u.x = (unsigned)f2bf(v0) | ((unsigned)f2bf(v1) << 16);
        u.y = (unsigned)f2bf(v2) | ((unsigned)f2bf(v3) << 16);
        *reinterpret_cast<uint2*>(&xT[l][4*q]) = u;
    }
    sPart[l][w] = csum;                          // thread's 16-channel partial for pixel l
    __syncthreads();

    // Stage C: D[o][pix] = A(Wsum) x B(xT^T); b128 read path identical to round 1
    f32x4 acc[4];
#pragma unroll
    for (int nt = 0; nt < 4; ++nt) acc[nt] = (f32x4){0.f, 0.f, 0.f, 0.f};

#pragma unroll 1
    for (int ks = 0; ks < 4; ++ks) {
        bf16x8 bfr[4];
#pragma unroll
        for (int nt = 0; nt < 4; ++nt)   // lane: n = pix = lo16+16nt, k = 8 contiguous c
            bfr[nt] = *reinterpret_cast<const bf16x8*>(&xT[nt*16 + lo16][ks*32 + g4*8]);
#pragma unroll
        for (int nt = 0; nt < 4; ++nt)
            acc[nt] = __builtin_amdgcn_mfma_f32_16x16x32_bf16(afrag[ks], bfr[nt], acc[nt], 0, 0, 0);
    }

    // Epilogue: out[o,p] = s[p] * (dot + bsum[o]); D row = g4*4+r, col = lo16 (+16nt)
    const int o0 = w*16 + g4*4;
    const float4 bs4 = *reinterpret_cast<const float4*>(bsum + o0);
    float* ob = out + (size_t)bIdx * OO * HWp + hw;
#pragma unroll
    for (int nt = 0; nt < 4; ++nt) {
        const int pp = nt*16 + lo16;
        float sv = 0.f;
#pragma unroll
        for (int q = 0; q < 8; ++q) sv += sPart[pp][q];
#pragma unroll
        for (int r = 0; r < 4; ++r) {
            const float bsv = (r == 0) ? bs4.x : (r == 1) ? bs4.y : (r == 2) ? bs4.z : bs4.w;
            ob[(size_t)(o0 + r) * HWp + pp] = (acc[nt][r] + bsv) * sv;
        }
    }
}

extern "C" void kernel_launch(void* const* d_in, const int* in_sizes, int n_in,
                              void* d_out, int out_size, void* d_ws, size_t ws_size,
                              hipStream_t stream) {
    const float* x  = (const float*)d_in[0];
    // d_in[1] offsets, d_in[2] tumor_center: mathematically dead (grid_sample on 1x1 input)
    const float* kw = (const float*)d_in[3];
    const float* kb = (const float*)d_in[4];
    float* outp = (float*)d_out;

    unsigned short* wfrag = (unsigned short*)d_ws;                 // 128*128 bf16 = 32 KB
    float* bsum = (float*)((char*)d_ws + 32768);                   // 128 f32

    prep_kernel<<<dim3(64), dim3(256), 0, stream>>>(kw, kb, wfrag, bsum);
    conv_kernel<<<dim3(NPIX / TILE), dim3(512), 0, stream>>>(x, wfrag, bsum, outp);
}

// Round 5
// 35.320 us; speedup vs baseline: 3.8287x; 3.8287x over previous
//
#include <hip/hip_runtime.h>
#include <hip/hip_bf16.h>

#define BB   4
#define CC   128
#define HH   192
#define WWd  192
#define HWp  (HH*WWd)      // 36864
#define OO   128
#define KK   7
#define NPIX (BB*HWp)      // 147456
#define TILE 64
// shared buffer views:
//   stage A/B:  xc[c][p]  = buf + c*128 + p*2          (128ch x 64pix bf16, 16 KB)
//   stage B2/C: xT[p][c]  = buf + p*272 + c*2          (64pix x 128ch bf16, pitch 136 shorts)
#define BUF_BYTES 17408

typedef short bf16x8 __attribute__((ext_vector_type(8)));
typedef float f32x4  __attribute__((ext_vector_type(4)));

static __device__ __forceinline__ unsigned f2bf(float f) {
    union { __hip_bfloat16 h; unsigned short u; } cvt;
    cvt.h = __float2bfloat16(f);
    return (unsigned)cvt.u;
}

// ---- prep: Wsum[o][c] = sum_k kernel_w[o*7+k, c] -> bf16 in MFMA A-frag order;
//      bsum[o] = sum_k kernel_b[o*7+k] (fp32).  (validated in round 1)
__global__ __launch_bounds__(256) void prep_kernel(const float* __restrict__ kw,
                                                   const float* __restrict__ kb,
                                                   unsigned short* __restrict__ wfrag,
                                                   float* __restrict__ bsum) {
    int tid = blockIdx.x * 256 + threadIdx.x;   // 0..16383
    int o = tid >> 7, c = tid & 127;
    float s = 0.f;
#pragma unroll
    for (int k = 0; k < KK; ++k) s += kw[(o*KK + k)*CC + c];
    // conv reads: afrag[mt][ks] of wave w lane l elem j <-> o = w*32+mt*16+(l&15), c = ks*32+(l>>4)*8+j
    int wv = o >> 5, mt = (o >> 4) & 1, lo = o & 15;
    int ks = c >> 5, g = (c >> 3) & 3, j = c & 7;
    int idx = ((((wv*2 + mt)*4 + ks)*64) + (lo + 16*g))*8 + j;
    wfrag[idx] = (unsigned short)f2bf(s);
    if (c == 0) {
        float bs = 0.f;
#pragma unroll
        for (int k = 0; k < KK; ++k) bs += kb[o*KK + k];
        bsum[o] = bs;
    }
}

// ---- main: 256 threads = 4 waves; block = 64 pixels x 128 outputs; wave = 32 outputs.
// Single reused LDS buffer (18 KB total incl. sPart) -> 8 blocks/CU occupancy cap.
__global__ __launch_bounds__(256, 8) void conv_kernel(const float* __restrict__ x,
                                                      const unsigned short* __restrict__ wfrag,
                                                      const float* __restrict__ bsum,
                                                      float* __restrict__ out) {
    __shared__ __align__(16) unsigned char buf[BUF_BYTES];
    __shared__ float sPart[4][TILE];

    const int t = threadIdx.x;
    const int w = t >> 6;            // wave 0..3: outputs [w*32, w*32+32)
    const int l = t & 63;
    const int lo16 = l & 15, g4 = l >> 4;

    const int pixBase = blockIdx.x * TILE;
    const int bIdx   = pixBase / HWp;
    const int hwBase = pixBase - bIdx * HWp;     // multiple of 64
    const float* xb  = x + (size_t)bIdx * CC * HWp + hwBase;

    // ---- Stage A: coalesced float4 loads -> bf16 -> xc[c][p]; fp32 channel partials
    {
        const int p4 = lo16 * 4;
        float pa = 0.f, pb = 0.f, pc = 0.f, pd = 0.f;
#pragma unroll
        for (int it = 0; it < 8; ++it) {
            const int c = it*16 + w*4 + g4;
            const float4 v = *reinterpret_cast<const float4*>(xb + (size_t)c * HWp + p4);
            pa += v.x; pb += v.y; pc += v.z; pd += v.w;
            uint2 u;
            u.x = f2bf(v.x) | (f2bf(v.y) << 16);
            u.y = f2bf(v.z) | (f2bf(v.w) << 16);
            *reinterpret_cast<uint2*>(&buf[c*128 + p4*2]) = u;
        }
        // reduce across the 4 channel-subgroups (lanes l, l^16, l^32, l^48 share p4)
        pa += __shfl_xor(pa, 16); pa += __shfl_xor(pa, 32);
        pb += __shfl_xor(pb, 16); pb += __shfl_xor(pb, 32);
        pc += __shfl_xor(pc, 16); pc += __shfl_xor(pc, 32);
        pd += __shfl_xor(pd, 16); pd += __shfl_xor(pd, 32);
        if (l < 16)
            *reinterpret_cast<float4*>(&sPart[w][p4]) = make_float4(pa, pb, pc, pd);
    }
    __syncthreads();

    // ---- Stage B: gather transpose into 16 packed regs (pixel l, channels w*32..+31)
    unsigned pk[16];
    {
        const int p2 = l * 2;
#pragma unroll
        for (int i = 0; i < 4; ++i)
#pragma unroll
            for (int h = 0; h < 4; ++h) {
                const int c = w*32 + i*8 + h*2;
                const unsigned e0 = *reinterpret_cast<const unsigned short*>(&buf[c*128 + p2]);
                const unsigned e1 = *reinterpret_cast<const unsigned short*>(&buf[(c+1)*128 + p2]);
                pk[i*4 + h] = e0 | (e1 << 16);
            }
    }
    __syncthreads();   // all reads of xc done before overwrite

    // ---- Stage B2: write xT[p][c] with b128
#pragma unroll
    for (int i = 0; i < 4; ++i) {
        uint4 q4 = make_uint4(pk[i*4+0], pk[i*4+1], pk[i*4+2], pk[i*4+3]);
        *reinterpret_cast<uint4*>(&buf[l*272 + w*64 + i*16]) = q4;
    }
    __syncthreads();

    // ---- Stage C: D[o][pix] = A(Wsum) x B(xT^T); read path identical to round 1
    f32x4 acc[2][4];
#pragma unroll
    for (int mt = 0; mt < 2; ++mt)
#pragma unroll
        for (int nt = 0; nt < 4; ++nt)
            acc[mt][nt] = (f32x4){0.f, 0.f, 0.f, 0.f};

    const unsigned short* wf = wfrag + (size_t)w * 2*4*64*8;
    for (int ks = 0; ks < 4; ++ks) {
        const bf16x8 a0 = *reinterpret_cast<const bf16x8*>(wf + ((size_t)(0*4 + ks)*64 + l)*8);
        const bf16x8 a1 = *reinterpret_cast<const bf16x8*>(wf + ((size_t)(1*4 + ks)*64 + l)*8);
        bf16x8 bfr[4];
#pragma unroll
        for (int nt = 0; nt < 4; ++nt)  // lane: n = pix = lo16+16nt, k = 8 contiguous c
            bfr[nt] = *reinterpret_cast<const bf16x8*>(&buf[(nt*16 + lo16)*272 + ks*64 + g4*16]);
#pragma unroll
        for (int nt = 0; nt < 4; ++nt) {
            acc[0][nt] = __builtin_amdgcn_mfma_f32_16x16x32_bf16(a0, bfr[nt], acc[0][nt], 0, 0, 0);
            acc[1][nt] = __builtin_amdgcn_mfma_f32_16x16x32_bf16(a1, bfr[nt], acc[1][nt], 0, 0, 0);
        }
    }

    // ---- Epilogue: out[o,p] = s[p] * (dot + bsum[o]); D row = g4*4+r, col = lo16 (+16nt)
    float* ob = out + (size_t)bIdx * OO * HWp + hwBase + lo16;
#pragma unroll
    for (int nt = 0; nt < 4; ++nt) {
        const int pp = nt*16 + lo16;
        const float sv = sPart[0][pp] + sPart[1][pp] + sPart[2][pp] + sPart[3][pp];
#pragma unroll
        for (int mt = 0; mt < 2; ++mt) {
            const int o0 = w*32 + mt*16 + g4*4;
            const float4 bs4 = *reinterpret_cast<const float4*>(bsum + o0);
#pragma unroll
            for (int r = 0; r < 4; ++r) {
                const float bsv = (r == 0) ? bs4.x : (r == 1) ? bs4.y : (r == 2) ? bs4.z : bs4.w;
                ob[(size_t)(o0 + r) * HWp + nt*16] = (acc[mt][nt][r] + bsv) * sv;
            }
        }
    }
}

extern "C" void kernel_launch(void* const* d_in, const int* in_sizes, int n_in,
                              void* d_out, int out_size, void* d_ws, size_t ws_size,
                              hipStream_t stream) {
    const float* x  = (const float*)d_in[0];
    // d_in[1] offsets, d_in[2] tumor_center: mathematically dead (grid_sample on 1x1 input)
    const float* kw = (const float*)d_in[3];
    const float* kb = (const float*)d_in[4];
    float* outp = (float*)d_out;

    unsigned short* wfrag = (unsigned short*)d_ws;                 // 128*128 bf16 = 32 KB
    float* bsum = (float*)((char*)d_ws + 32768);                   // 128 f32

    prep_kernel<<<dim3(64), dim3(256), 0, stream>>>(kw, kb, wfrag, bsum);
    conv_kernel<<<dim3(NPIX / TILE), dim3(256), 0, stream>>>(x, wfrag, bsum, outp);
}

// Round 6
// 33.730 us; speedup vs baseline: 4.0092x; 1.0471x over previous
//
#include <hip/hip_runtime.h>
#include <hip/hip_bf16.h>

#define BB   4
#define CC   128
#define HH   192
#define WWd  192
#define HWp  (HH*WWd)      // 36864
#define OO   128
#define KK   7
#define NPIX (BB*HWp)      // 147456
#define TILE 64
#define XT_PITCH_B 272     // bytes per pixel row (136 shorts; 16B-aligned, read-conflict-free)

typedef short bf16x8 __attribute__((ext_vector_type(8)));
typedef float f32x4  __attribute__((ext_vector_type(4)));

static __device__ __forceinline__ unsigned f2bf(float f) {
    union { __hip_bfloat16 h; unsigned short u; } cvt;
    cvt.h = __float2bfloat16(f);
    return (unsigned)cvt.u;
}

// ---- prep: Wsum[o][c] = sum_k kernel_w[o*7+k, c] -> bf16 in MFMA A-frag order;
//      bsum[o] = sum_k kernel_b[o*7+k] (fp32).  (validated rounds 1/3/5)
__global__ __launch_bounds__(256) void prep_kernel(const float* __restrict__ kw,
                                                   const float* __restrict__ kb,
                                                   unsigned short* __restrict__ wfrag,
                                                   float* __restrict__ bsum) {
    int tid = blockIdx.x * 256 + threadIdx.x;   // 0..16383
    int o = tid >> 7, c = tid & 127;
    float s = 0.f;
#pragma unroll
    for (int k = 0; k < KK; ++k) s += kw[(o*KK + k)*CC + c];
    // conv reads: afrag[mt][ks] of wave w lane l elem j <-> o = w*32+mt*16+(l&15), c = ks*32+(l>>4)*8+j
    int wv = o >> 5, mt = (o >> 4) & 1, lo = o & 15;
    int ks = c >> 5, g = (c >> 3) & 3, j = c & 7;
    int idx = ((((wv*2 + mt)*4 + ks)*64) + (lo + 16*g))*8 + j;
    wfrag[idx] = (unsigned short)f2bf(s);
    if (c == 0) {
        float bs = 0.f;
#pragma unroll
        for (int k = 0; k < KK; ++k) bs += kb[o*KK + k];
        bsum[o] = bs;
    }
}

// ---- main: 256 threads = 4 waves; block = 64 pixels x 128 outputs; wave = 32 outputs.
// Stage A: lane<->pixel scalar loads (fully coalesced 256B/instr); each thread packs
// 4-channel quads of ONE pixel -> ds_write_b64 directly into xT[pix][c].
// ONE barrier, zero LDS reads before MFMA. Stage C identical to validated R1/R5 path.
__global__ __launch_bounds__(256, 4) void conv_kernel(const float* __restrict__ x,
                                                      const unsigned short* __restrict__ wfrag,
                                                      const float* __restrict__ bsum,
                                                      float* __restrict__ out) {
    __shared__ __align__(16) unsigned char xTb[TILE * XT_PITCH_B];  // 17408 B
    __shared__ float sPart[4][TILE];                                 // 1 KB

    const int t = threadIdx.x;
    const int w = t >> 6;            // wave 0..3: outputs [w*32, w*32+32), channels [w*32, w*32+32) in stage A
    const int l = t & 63;
    const int lo16 = l & 15, g4 = l >> 4;

    const int pixBase = blockIdx.x * TILE;
    const int bIdx   = pixBase / HWp;
    const int hwBase = pixBase - bIdx * HWp;     // multiple of 64
    const float* xb  = x + (size_t)bIdx * CC * HWp + hwBase + l;   // this lane's pixel column

    // A-fragments hoisted (wfrag is L2-resident): 2 m-tiles x 4 k-steps = 32 VGPR
    bf16x8 afrag[2][4];
    const unsigned short* wf = wfrag + (size_t)w * 2*4*64*8;
#pragma unroll
    for (int mt = 0; mt < 2; ++mt)
#pragma unroll
        for (int ks = 0; ks < 4; ++ks)
            afrag[mt][ks] = *reinterpret_cast<const bf16x8*>(wf + ((size_t)(mt*4 + ks)*64 + l)*8);

    // ---- Stage A: 32 coalesced scalar loads (channels w*32..w*32+31 of pixel l)
    float v[32];
#pragma unroll
    for (int i = 0; i < 8; ++i) {
        const int c0 = w*32 + i*4;
#pragma unroll
        for (int j = 0; j < 4; ++j)
            v[i*4 + j] = xb[(size_t)(c0 + j) * HWp];
    }
    float csum = 0.f;
#pragma unroll
    for (int i = 0; i < 32; ++i) csum += v[i];
    sPart[w][l] = csum;
#pragma unroll
    for (int i = 0; i < 8; ++i) {
        uint2 u;
        u.x = f2bf(v[i*4+0]) | (f2bf(v[i*4+1]) << 16);
        u.y = f2bf(v[i*4+2]) | (f2bf(v[i*4+3]) << 16);
        *reinterpret_cast<uint2*>(&xTb[l*XT_PITCH_B + (w*32 + i*4)*2]) = u;
    }
    __syncthreads();

    // ---- Stage C: D[o][pix] = A(Wsum) x B(xT^T)
    f32x4 acc[2][4];
#pragma unroll
    for (int mt = 0; mt < 2; ++mt)
#pragma unroll
        for (int nt = 0; nt < 4; ++nt)
            acc[mt][nt] = (f32x4){0.f, 0.f, 0.f, 0.f};

    for (int ks = 0; ks < 4; ++ks) {
        bf16x8 bfr[4];
#pragma unroll
        for (int nt = 0; nt < 4; ++nt)  // lane: n = pix = lo16+16nt, k = 8 contiguous c
            bfr[nt] = *reinterpret_cast<const bf16x8*>(
                &xTb[(nt*16 + lo16)*XT_PITCH_B + ks*64 + g4*16]);
#pragma unroll
        for (int nt = 0; nt < 4; ++nt) {
            acc[0][nt] = __builtin_amdgcn_mfma_f32_16x16x32_bf16(afrag[0][ks], bfr[nt], acc[0][nt], 0, 0, 0);
            acc[1][nt] = __builtin_amdgcn_mfma_f32_16x16x32_bf16(afrag[1][ks], bfr[nt], acc[1][nt], 0, 0, 0);
        }
    }

    // ---- Epilogue: out[o,p] = s[p] * (dot + bsum[o]); D row = g4*4+r, col = lo16 (+16nt)
    float* ob = out + (size_t)bIdx * OO * HWp + hwBase + lo16;
#pragma unroll
    for (int nt = 0; nt < 4; ++nt) {
        const int pp = nt*16 + lo16;
        const float sv = sPart[0][pp] + sPart[1][pp] + sPart[2][pp] + sPart[3][pp];
#pragma unroll
        for (int mt = 0; mt < 2; ++mt) {
            const int o0 = w*32 + mt*16 + g4*4;
            const float4 bs4 = *reinterpret_cast<const float4*>(bsum + o0);
#pragma unroll
            for (int r = 0; r < 4; ++r) {
                const float bsv = (r == 0) ? bs4.x : (r == 1) ? bs4.y : (r == 2) ? bs4.z : bs4.w;
                ob[(size_t)(o0 + r) * HWp + nt*16] = (acc[mt][nt][r] + bsv) * sv;
            }
        }
    }
}

extern "C" void kernel_launch(void* const* d_in, const int* in_sizes, int n_in,
                              void* d_out, int out_size, void* d_ws, size_t ws_size,
                              hipStream_t stream) {
    const float* x  = (const float*)d_in[0];
    // d_in[1] offsets, d_in[2] tumor_center: mathematically dead (grid_sample on 1x1 input)
    const float* kw = (const float*)d_in[3];
    const float* kb = (const float*)d_in[4];
    float* outp = (float*)d_out;

    unsigned short* wfrag = (unsigned short*)d_ws;                 // 128*128 bf16 = 32 KB
    float* bsum = (float*)((char*)d_ws + 32768);                   // 128 f32

    prep_kernel<<<dim3(64), dim3(256), 0, stream>>>(kw, kb, wfrag, bsum);
    conv_kernel<<<dim3(NPIX / TILE), dim3(256), 0, stream>>>(x, wfrag, bsum, outp);
}